// Round 1
// baseline (170.866 us; speedup 1.0000x reference)
//
#include <hip/hip_runtime.h>

// y[n,c,h,w] = x[n,c,h,w] * w[c] + b[c]
// x: (32, 64, 224, 224) fp32. HW = 50176 floats = 12544 float4 (vector never
// straddles a channel boundary). Memory-bound: target HBM BW ceiling.

__global__ __launch_bounds__(256) void scale_kernel(
    const float4* __restrict__ x,
    const float*  __restrict__ w,
    const float*  __restrict__ b,
    float4*       __restrict__ y,
    long long nvec) {
    const long long HWV = 12544;  // 224*224/4 float4s per (n,c) plane
    long long i = (long long)blockIdx.x * blockDim.x + threadIdx.x;
    const long long stride = (long long)gridDim.x * blockDim.x;
    for (; i < nvec; i += stride) {
        int c = (int)((i / HWV) & 63);   // 64 channels, pow2
        const float wc = w[c];
        const float bc = b[c];
        float4 v = x[i];
        v.x = fmaf(v.x, wc, bc);
        v.y = fmaf(v.y, wc, bc);
        v.z = fmaf(v.z, wc, bc);
        v.w = fmaf(v.w, wc, bc);
        y[i] = v;
    }
}

extern "C" void kernel_launch(void* const* d_in, const int* in_sizes, int n_in,
                              void* d_out, int out_size, void* d_ws, size_t ws_size,
                              hipStream_t stream) {
    const float* x = (const float*)d_in[0];
    const float* w = (const float*)d_in[1];
    const float* b = (const float*)d_in[2];
    float* y = (float*)d_out;

    const long long n = (long long)out_size;      // 102,760,448 elements
    const long long nvec = n / 4;                 // 25,690,112 float4s

    const int block = 256;
    long long want = (nvec + block - 1) / block;
    int grid = (int)(want < 2048 ? want : 2048);  // grid-stride the rest

    scale_kernel<<<grid, block, 0, stream>>>(
        (const float4*)x, w, b, (float4*)y, nvec);
}

// Round 2
// 168.950 us; speedup vs baseline: 1.0113x; 1.0113x over previous
//
#include <hip/hip_runtime.h>

// y[n,c,h,w] = x[n,c,h,w] * w[c] + b[c]
// x: (32, 64, 224, 224) fp32.
// One workgroup per (n,c) plane: plane = 224*224 = 50176 floats = 12544 float4
// = exactly 49 iterations of 256 threads. No divisions in the hot loop.

__global__ __launch_bounds__(256) void scale_kernel(
    const float4* __restrict__ x,
    const float*  __restrict__ w,
    const float*  __restrict__ b,
    float4*       __restrict__ y) {
    const int HWV = 12544;                 // float4s per (n,c) plane
    const int plane = blockIdx.x;          // 0..2047  (= n*64 + c)
    const int c = plane & 63;              // 64 channels, pow2
    const float wc = w[c];
    const float bc = b[c];

    const float4* __restrict__ xp = x + (long long)plane * HWV;
    float4*       __restrict__ yp = y + (long long)plane * HWV;

    #pragma unroll 4
    for (int i = 0; i < 49; ++i) {
        const int idx = threadIdx.x + (i << 8);   // i*256
        float4 v = xp[idx];
        v.x = fmaf(v.x, wc, bc);
        v.y = fmaf(v.y, wc, bc);
        v.z = fmaf(v.z, wc, bc);
        v.w = fmaf(v.w, wc, bc);
        yp[idx] = v;
    }
}

extern "C" void kernel_launch(void* const* d_in, const int* in_sizes, int n_in,
                              void* d_out, int out_size, void* d_ws, size_t ws_size,
                              hipStream_t stream) {
    const float* x = (const float*)d_in[0];
    const float* w = (const float*)d_in[1];
    const float* b = (const float*)d_in[2];
    float* y = (float*)d_out;

    const int planes = 32 * 64;  // 2048 workgroups = 8/CU
    scale_kernel<<<planes, 256, 0, stream>>>(
        (const float4*)x, w, b, (float4*)y);
}

// Round 3
// 152.820 us; speedup vs baseline: 1.1181x; 1.1055x over previous
//
#include <hip/hip_runtime.h>

// y[n,c,h,w] = x[n,c,h,w] * w[c] + b[c]
// x: (32, 64, 224, 224) fp32. One workgroup per (n,c) plane.
// Plane = 50176 floats = 12544 float4 = 49 * 256.
// 6 batches of 8 float4 (8 loads in flight, then 8 stores) + 1 tail.
// Nontemporal hints: pure streaming, zero reuse, don't thrash L2.

typedef float f32x4 __attribute__((ext_vector_type(4)));

__global__ __launch_bounds__(256) void scale_kernel(
    const f32x4* __restrict__ x,
    const float* __restrict__ w,
    const float* __restrict__ b,
    f32x4*       __restrict__ y) {
    const int plane = blockIdx.x;          // 0..2047  (= n*64 + c)
    const int c = plane & 63;
    const float wc = w[c];
    const float bc = b[c];

    const long long base = (long long)plane * 12544;
    const f32x4* __restrict__ xp = x + base;
    f32x4*       __restrict__ yp = y + base;
    const int tid = threadIdx.x;

    for (int bi = 0; bi < 6; ++bi) {
        const int o = bi * 2048 + tid;     // 8*256 = 2048 per batch
        f32x4 v[8];
        #pragma unroll
        for (int j = 0; j < 8; ++j)
            v[j] = __builtin_nontemporal_load(&xp[o + j * 256]);
        #pragma unroll
        for (int j = 0; j < 8; ++j) {
            f32x4 t = v[j];
            t.x = fmaf(t.x, wc, bc);
            t.y = fmaf(t.y, wc, bc);
            t.z = fmaf(t.z, wc, bc);
            t.w = fmaf(t.w, wc, bc);
            __builtin_nontemporal_store(t, &yp[o + j * 256]);
        }
    }
    {   // tail iteration 49 = 6*8 + 1
        const int o = 12288 + tid;
        f32x4 t = __builtin_nontemporal_load(&xp[o]);
        t.x = fmaf(t.x, wc, bc);
        t.y = fmaf(t.y, wc, bc);
        t.z = fmaf(t.z, wc, bc);
        t.w = fmaf(t.w, wc, bc);
        __builtin_nontemporal_store(t, &yp[o]);
    }
}

extern "C" void kernel_launch(void* const* d_in, const int* in_sizes, int n_in,
                              void* d_out, int out_size, void* d_ws, size_t ws_size,
                              hipStream_t stream) {
    const float* x = (const float*)d_in[0];
    const float* w = (const float*)d_in[1];
    const float* b = (const float*)d_in[2];
    float* y = (float*)d_out;

    const int planes = 32 * 64;  // 2048 workgroups
    scale_kernel<<<planes, 256, 0, stream>>>(
        (const f32x4*)x, w, b, (f32x4*)y);
}